// Round 12
// baseline (456.728 us; speedup 1.0000x reference)
//
#include <hip/hip_runtime.h>

#define N_USERS 50000
#define N_ENTITIES 100000
#define N_RELATIONS 16
#define N_EDGES 3200000
#define NNZ 2500000
#define CH 64

#define RPB 64
#define NB_E 1563                 // ceil(N_ENTITIES/64) fine buckets
#define NB_U 782                  // ceil(N_USERS/64)
#define NBUCKETS (NB_E + NB_U)    // 2345
#define STAGE 3840                // sort LDS staging capacity (max bucket ~3500)

#define NCE 49                    // entity coarse buckets (2048 rows each)
#define NCU 25                    // user coarse buckets (2048 rows each)
#define CAPC_E 67072              // mean 65306, +~7 sigma
#define CAPC_U 104448             // mean 100000, +~14 sigma
#define NCU_DOUT 14               // user coarse buckets hosted in d_out scratch

#define PA_KG 512                 // pass-A KG blocks (2x: occupancy for latency hiding)
#define PA_U  384                 // pass-A user blocks
#define PACK_BLOCKS 1563          // bf16-pack blocks appended to pass-A grid
#define SE 15                     // pass-B sub-blocks per entity coarse bucket
#define SU 24                     // pass-B sub-blocks per user coarse bucket

typedef float v2f __attribute__((ext_vector_type(2)));

__device__ __forceinline__ unsigned short f2bf(float f) {
    unsigned u = __float_as_uint(f);
    u += 0x7FFF + ((u >> 16) & 1);   // round-to-nearest-even
    return (unsigned short)(u >> 16);
}

// unpack a packed bf16 pair into {lo, hi} as f32x2 (2 VALU ops)
__device__ __forceinline__ v2f bfpair(unsigned q) {
    v2f r;
    r.x = __uint_as_float(q << 16);
    r.y = __uint_as_float(q & 0xFFFF0000u);
    return r;
}

__device__ __forceinline__ int wave_incl_scan(int v, int lane) {
    int s = v;
    #pragma unroll
    for (int d = 1; d < 64; d <<= 1) {
        int x = __shfl_up(s, d, 64);
        if (lane >= d) s += x;
    }
    return s;
}

// ---------------------------------------------------------------------------
// Pass A: coarse partition (2048-row buckets) with per-block contiguous
// reservations (~1x write amp) + EXACT per-fine-bucket counts (LDS
// histogram) + bf16 pack of the entity table. The coarse histogram is
// DERIVED from the fine histogram at flush time (histC[i>>5] += histF[i])
// — removes 5.7M contended per-edge LDS atomics. Payload: fine-within-
// coarse in bits 27-31; low fields unchanged.
// ---------------------------------------------------------------------------
__global__ void __launch_bounds__(1024)
passA_kernel(const int* __restrict__ head, const int* __restrict__ tail,
             const int* __restrict__ type, const float* __restrict__ maskp,
             const int* __restrict__ irows, const int* __restrict__ icols,
             const float* __restrict__ ivals,
             const float4* __restrict__ entity_emb, ushort4* __restrict__ cur_bf,
             int* __restrict__ fineCnt, int* __restrict__ cCurE,
             int* __restrict__ cCurU,
             int2* __restrict__ cbE, int2* __restrict__ cbU_d,
             int2* __restrict__ cbU_w) {
    __shared__ int histF[NB_E];
    __shared__ int histC[64];
    __shared__ int lbase[64];
    __shared__ int2* utab[NCU];
    const int blk = blockIdx.x;
    const int t = threadIdx.x;

    if (blk >= PA_KG + PA_U) {
        // ---- bf16 pack: curA = bf16(entity_emb) ----
        const int ne4 = N_ENTITIES * CH / 4;
        int i = (blk - PA_KG - PA_U) * 1024 + t;
        if (i < ne4) {
            float4 v = entity_emb[i];
            ushort4 bq;
            bq.x = f2bf(v.x); bq.y = f2bf(v.y); bq.z = f2bf(v.z); bq.w = f2bf(v.w);
            cur_bf[i] = bq;
        }
        return;
    }

    if (blk < PA_KG) {
        // ---- KG edges ----
        for (int i = t; i < NB_E; i += 1024) histF[i] = 0;
        if (t < NCE) histC[t] = 0;
        __syncthreads();
        const int chunk = (N_EDGES + PA_KG - 1) / PA_KG;
        int base = blk * chunk, lim = min(base + chunk, N_EDGES);
        for (int i = base + t; i < lim; i += 1024)
            atomicAdd(&histF[head[i] >> 6], 1);
        __syncthreads();
        for (int i = t; i < NB_E; i += 1024) {
            int c = histF[i];
            if (c) {
                atomicAdd(&fineCnt[NB_U + i], c);
                atomicAdd(&histC[i >> 5], c);     // derive coarse from fine
            }
        }
        __syncthreads();
        if (t < NCE) {
            int c = histC[t];
            lbase[t] = c ? atomicAdd(&cCurE[t], c) : 0;
            histC[t] = 0;
        }
        __syncthreads();
        int i = base + t;
        for (; i + 3072 < lim; i += 4096) {
            int i0 = i, i1 = i + 1024, i2 = i + 2048, i3 = i + 3072;
            int h0 = head[i0], h1 = head[i1], h2 = head[i2], h3 = head[i3];
            int x0 = tail[i0] | ((type[i0] - 1) << 17) | ((h0 & 63) << 21) | (((h0 >> 6) & 31) << 27);
            int x1 = tail[i1] | ((type[i1] - 1) << 17) | ((h1 & 63) << 21) | (((h1 >> 6) & 31) << 27);
            int x2 = tail[i2] | ((type[i2] - 1) << 17) | ((h2 & 63) << 21) | (((h2 >> 6) & 31) << 27);
            int x3 = tail[i3] | ((type[i3] - 1) << 17) | ((h3 & 63) << 21) | (((h3 >> 6) & 31) << 27);
            float m0 = maskp[i0], m1 = maskp[i1], m2 = maskp[i2], m3 = maskp[i3];
            int c0 = h0 >> 11, c1 = h1 >> 11, c2 = h2 >> 11, c3 = h3 >> 11;
            int l0 = lbase[c0] + atomicAdd(&histC[c0], 1);
            int l1 = lbase[c1] + atomicAdd(&histC[c1], 1);
            int l2 = lbase[c2] + atomicAdd(&histC[c2], 1);
            int l3 = lbase[c3] + atomicAdd(&histC[c3], 1);
            if (l0 < CAPC_E) cbE[(size_t)c0 * CAPC_E + l0] = make_int2(x0, __float_as_int(m0));
            if (l1 < CAPC_E) cbE[(size_t)c1 * CAPC_E + l1] = make_int2(x1, __float_as_int(m1));
            if (l2 < CAPC_E) cbE[(size_t)c2 * CAPC_E + l2] = make_int2(x2, __float_as_int(m2));
            if (l3 < CAPC_E) cbE[(size_t)c3 * CAPC_E + l3] = make_int2(x3, __float_as_int(m3));
        }
        for (; i < lim; i += 1024) {
            int h = head[i];
            int x = tail[i] | ((type[i] - 1) << 17) | ((h & 63) << 21) | (((h >> 6) & 31) << 27);
            int c = h >> 11;
            int loc = lbase[c] + atomicAdd(&histC[c], 1);
            if (loc < CAPC_E)
                cbE[(size_t)c * CAPC_E + loc] = make_int2(x, __float_as_int(maskp[i]));
        }
    } else {
        // ---- user interactions ----
        if (t < NCU)
            utab[t] = (t < NCU_DOUT) ? (cbU_d + (size_t)t * CAPC_U)
                                     : (cbU_w + (size_t)(t - NCU_DOUT) * CAPC_U);
        for (int i = t; i < NB_U; i += 1024) histF[i] = 0;
        if (t < NCU) histC[t] = 0;
        __syncthreads();
        const int ub = blk - PA_KG;
        const int chunk = (NNZ + PA_U - 1) / PA_U;
        int base = ub * chunk, lim = min(base + chunk, NNZ);
        for (int i = base + t; i < lim; i += 1024)
            atomicAdd(&histF[irows[i] >> 6], 1);
        __syncthreads();
        for (int i = t; i < NB_U; i += 1024) {
            int c = histF[i];
            if (c) {
                atomicAdd(&fineCnt[i], c);
                atomicAdd(&histC[i >> 5], c);     // derive coarse from fine
            }
        }
        __syncthreads();
        if (t < NCU) {
            int c = histC[t];
            lbase[t] = c ? atomicAdd(&cCurU[t], c) : 0;
            histC[t] = 0;
        }
        __syncthreads();
        int i = base + t;
        for (; i + 3072 < lim; i += 4096) {
            int i0 = i, i1 = i + 1024, i2 = i + 2048, i3 = i + 3072;
            int r0 = irows[i0], r1 = irows[i1], r2 = irows[i2], r3 = irows[i3];
            int x0 = icols[i0] | ((r0 & 63) << 17) | (((r0 >> 6) & 31) << 27);
            int x1 = icols[i1] | ((r1 & 63) << 17) | (((r1 >> 6) & 31) << 27);
            int x2 = icols[i2] | ((r2 & 63) << 17) | (((r2 >> 6) & 31) << 27);
            int x3 = icols[i3] | ((r3 & 63) << 17) | (((r3 >> 6) & 31) << 27);
            float v0 = ivals[i0], v1 = ivals[i1], v2 = ivals[i2], v3 = ivals[i3];
            int c0 = r0 >> 11, c1 = r1 >> 11, c2 = r2 >> 11, c3 = r3 >> 11;
            int l0 = lbase[c0] + atomicAdd(&histC[c0], 1);
            int l1 = lbase[c1] + atomicAdd(&histC[c1], 1);
            int l2 = lbase[c2] + atomicAdd(&histC[c2], 1);
            int l3 = lbase[c3] + atomicAdd(&histC[c3], 1);
            if (l0 < CAPC_U) utab[c0][l0] = make_int2(x0, __float_as_int(v0));
            if (l1 < CAPC_U) utab[c1][l1] = make_int2(x1, __float_as_int(v1));
            if (l2 < CAPC_U) utab[c2][l2] = make_int2(x2, __float_as_int(v2));
            if (l3 < CAPC_U) utab[c3][l3] = make_int2(x3, __float_as_int(v3));
        }
        for (; i < lim; i += 1024) {
            int r = irows[i];
            int x = icols[i] | ((r & 63) << 17) | (((r >> 6) & 31) << 27);
            int c = r >> 11;
            int loc = lbase[c] + atomicAdd(&histC[c], 1);
            if (loc < CAPC_U) utab[c][loc] = make_int2(x, __float_as_int(ivals[i]));
        }
    }
}

// ---------------------------------------------------------------------------
// Scan: exclusive prefix over the 2345 exact fine-bucket counts ->
// fineBase (CSR bases) and fineCur (pass-B cursors).
// ---------------------------------------------------------------------------
__global__ void __launch_bounds__(512)
scan_kernel(const int* __restrict__ fineCnt, int* __restrict__ fineBase,
            int* __restrict__ fineCur) {
    __shared__ int wsums[8];
    __shared__ int carry_s;
    const int t = threadIdx.x, w = t >> 6, lane = t & 63;
    if (t == 0) carry_s = 0;
    __syncthreads();
    for (int base = 0; base < NBUCKETS; base += 512) {
        int i = base + t;
        int v = (i < NBUCKETS) ? fineCnt[i] : 0;
        int s = wave_incl_scan(v, lane);
        if (lane == 63) wsums[w] = s;
        __syncthreads();
        int carry = carry_s;
        if (w == 0) {
            int ws = (lane < 8) ? wsums[lane] : 0;
            int ss = wave_incl_scan(ws, lane);
            if (lane < 8) wsums[lane] = ss - ws;
        }
        __syncthreads();
        int excl = s - v + wsums[w] + carry;
        if (i < NBUCKETS) { fineBase[i] = excl; fineCur[i] = excl; }
        __syncthreads();
        if (t == 511) carry_s = excl + v;
        __syncthreads();
    }
}

// ---------------------------------------------------------------------------
// Pass B: fine partition with PER-BLOCK CONTIGUOUS RESERVATIONS (the rule:
// never per-edge global cursors — rounds 3/7 showed 7x write amplification).
// ---------------------------------------------------------------------------
__global__ void __launch_bounds__(1024)
passB_kernel(const int* __restrict__ cCurE, const int* __restrict__ cCurU,
             const int2* __restrict__ cbE, const int2* __restrict__ cbU_d,
             const int2* __restrict__ cbU_w,
             int* __restrict__ fineCur, int2* __restrict__ binAll) {
    __shared__ int h32[32];
    __shared__ int lb[32];
    const int blk = blockIdx.x, t = threadIdx.x;
    const int2* __restrict__ src;
    int cnt, sub, S, fid0;
    if (blk < NCE * SE) {
        int c = blk / SE; sub = blk % SE; S = SE;
        cnt = min(cCurE[c], CAPC_E);
        src = cbE + (size_t)c * CAPC_E;
        fid0 = NB_U + c * 32;
    } else {
        int c = (blk - NCE * SE) / SU; sub = (blk - NCE * SE) % SU; S = SU;
        cnt = min(cCurU[c], CAPC_U);
        src = (c < NCU_DOUT) ? cbU_d + (size_t)c * CAPC_U
                             : cbU_w + (size_t)(c - NCU_DOUT) * CAPC_U;
        fid0 = c * 32;
    }
    int len = (cnt + S - 1) / S;
    int b0 = sub * len, b1 = min(b0 + len, cnt);
    if (t < 32) h32[t] = 0;
    __syncthreads();
    for (int i = b0 + t; i < b1; i += 1024)
        atomicAdd(&h32[(src[i].x >> 27) & 31], 1);
    __syncthreads();
    if (t < 32) {
        int c2 = h32[t];
        lb[t] = c2 ? atomicAdd(&fineCur[fid0 + t], c2) : 0;
        h32[t] = 0;
    }
    __syncthreads();
    int i = b0 + t;
    for (; i + 3072 < b1; i += 4096) {
        int2 e0 = src[i], e1 = src[i + 1024], e2 = src[i + 2048], e3 = src[i + 3072];
        int f0 = (e0.x >> 27) & 31, f1 = (e1.x >> 27) & 31;
        int f2 = (e2.x >> 27) & 31, f3 = (e3.x >> 27) & 31;
        int l0 = lb[f0] + atomicAdd(&h32[f0], 1);
        int l1 = lb[f1] + atomicAdd(&h32[f1], 1);
        int l2 = lb[f2] + atomicAdd(&h32[f2], 1);
        int l3 = lb[f3] + atomicAdd(&h32[f3], 1);
        binAll[l0] = e0; binAll[l1] = e1; binAll[l2] = e2; binAll[l3] = e3;
    }
    for (; i < b1; i += 1024) {
        int2 e = src[i];
        int f = (e.x >> 27) & 31;
        binAll[lb[f] + atomicAdd(&h32[f], 1)] = e;
    }
}

// ---------------------------------------------------------------------------
// Fused sort + hop-1 aggregation: one block (512 thr = 8 waves) per bucket.
// Phase 1: load the whole bucket into REGISTERS (8 int2/thread) — binAll
// read exactly once. Phase 2: histogram + scan + scatter into the LDS sort
// buffer. Phase 3: write sorted bucket back (hop 2 needs it) + rowptr.
// Phase 4: aggregate straight from LDS, packed-math inner loop,
// res = emb + y epilogue.
// ---------------------------------------------------------------------------
__global__ void __launch_bounds__(512)
sortagg_kernel(int2* __restrict__ binAll, const int* __restrict__ fineCnt,
               const int* __restrict__ fineBase, int* __restrict__ rowptr,
               const uint2* __restrict__ cur64, const float* __restrict__ weight,
               unsigned short* __restrict__ nxt,
               const float4* __restrict__ src_e, const float4* __restrict__ src_u,
               float* __restrict__ res_e, float* __restrict__ res_u) {
    __shared__ int2   sbuf[STAGE];             // 30720 B (sorted bucket)
    __shared__ float4 wl4[N_RELATIONS * 16];   // 4 KB
    __shared__ int    hist[RPB];
    __shared__ int    offs[RPB + 1];

    const int b = blockIdx.x;
    const int t = threadIdx.x;
    const bool is_user = (b < NB_U);
    const int eb = b - NB_U;
    const int base = fineBase[b];
    int2* __restrict__ bin = binAll + base;
    const int cnt = min(fineCnt[b], STAGE);
    const int rsh = is_user ? 17 : 21;

    // ---- phase 1: bucket -> registers, histogram ----
    int2 ebuf[8];
    if (t < RPB) hist[t] = 0;
    #pragma unroll
    for (int j = 0; j < 8; ++j) {
        int idx = t + (j << 9);
        if (idx < cnt) ebuf[j] = bin[idx];
    }
    if (!is_user)
        for (int i = t; i < N_RELATIONS * 16; i += 512)
            wl4[i] = ((const float4*)weight)[i];
    __syncthreads();
    #pragma unroll
    for (int j = 0; j < 8; ++j) {
        int idx = t + (j << 9);
        if (idx < cnt) atomicAdd(&hist[(ebuf[j].x >> rsh) & 63], 1);
    }
    __syncthreads();
    // ---- phase 2: scan + scatter into LDS ----
    if (t < 64) {
        int v = hist[t];
        int s = wave_incl_scan(v, t);
        offs[t] = s - v;
        if (t == 63) offs[64] = s;
    }
    __syncthreads();
    if (t < RPB) hist[t] = 0;        // becomes cursor
    __syncthreads();
    #pragma unroll
    for (int j = 0; j < 8; ++j) {
        int idx = t + (j << 9);
        if (idx < cnt) {
            int r = (ebuf[j].x >> rsh) & 63;
            int k = atomicAdd(&hist[r], 1);
            sbuf[offs[r] + k] = ebuf[j];
        }
    }
    __syncthreads();
    // ---- phase 3: sorted writeback (for hop 2) + rowptr ----
    for (int i = t; i < cnt; i += 512) bin[i] = sbuf[i];
    if (t <= 64) rowptr[b * 65 + t] = base + offs[t];

    // ---- phase 4: aggregation from LDS ----
    const int w = t >> 6;            // wave 0..7
    const int lane = t & 63;
    const int g = lane >> 4;         // edge-group 0..3
    const int c2 = lane & 15;        // uint2 index within row (4 channels)

    #pragma unroll
    for (int rr = 0; rr < 8; ++rr) {
        const int row = (w << 3) + rr;
        const int s = offs[row], e = offs[row + 1];   // LOCAL sbuf indices
        v2f a01 = {0.f, 0.f}, a23 = {0.f, 0.f};
        int i = s;
        if (is_user) {
            for (; i + 15 < e; i += 16) {
                int2 pa = sbuf[i + g];
                int2 pb = sbuf[i + 4 + g];
                int2 pc = sbuf[i + 8 + g];
                int2 pd = sbuf[i + 12 + g];
                uint2 qa = cur64[(size_t)(pa.x & 0x1FFFF) * 16 + c2];
                uint2 qb = cur64[(size_t)(pb.x & 0x1FFFF) * 16 + c2];
                uint2 qc = cur64[(size_t)(pc.x & 0x1FFFF) * 16 + c2];
                uint2 qd = cur64[(size_t)(pd.x & 0x1FFFF) * 16 + c2];
                float sa = __int_as_float(pa.y);
                float sb = __int_as_float(pb.y);
                float sc = __int_as_float(pc.y);
                float sd = __int_as_float(pd.y);
                a01 += bfpair(qa.x) * sa;  a23 += bfpair(qa.y) * sa;
                a01 += bfpair(qb.x) * sb;  a23 += bfpair(qb.y) * sb;
                a01 += bfpair(qc.x) * sc;  a23 += bfpair(qc.y) * sc;
                a01 += bfpair(qd.x) * sd;  a23 += bfpair(qd.y) * sd;
            }
            for (; i + 7 < e; i += 8) {
                int2 pa = sbuf[i + g];
                int2 pb = sbuf[i + 4 + g];
                uint2 qa = cur64[(size_t)(pa.x & 0x1FFFF) * 16 + c2];
                uint2 qb = cur64[(size_t)(pb.x & 0x1FFFF) * 16 + c2];
                float sa = __int_as_float(pa.y);
                float sb = __int_as_float(pb.y);
                a01 += bfpair(qa.x) * sa;  a23 += bfpair(qa.y) * sa;
                a01 += bfpair(qb.x) * sb;  a23 += bfpair(qb.y) * sb;
            }
            for (; i < e; i += 4) {
                int idx = i + g;
                bool vld = idx < e;
                int2 p = sbuf[vld ? idx : i];
                uint2 q = cur64[(size_t)(p.x & 0x1FFFF) * 16 + c2];
                float sv = vld ? __int_as_float(p.y) : 0.f;
                a01 += bfpair(q.x) * sv;  a23 += bfpair(q.y) * sv;
            }
        } else {
            for (; i + 15 < e; i += 16) {
                int2 pa = sbuf[i + g];
                int2 pb = sbuf[i + 4 + g];
                int2 pc = sbuf[i + 8 + g];
                int2 pd = sbuf[i + 12 + g];
                uint2 qa = cur64[(size_t)(pa.x & 0x1FFFF) * 16 + c2];
                uint2 qb = cur64[(size_t)(pb.x & 0x1FFFF) * 16 + c2];
                uint2 qc = cur64[(size_t)(pc.x & 0x1FFFF) * 16 + c2];
                uint2 qd = cur64[(size_t)(pd.x & 0x1FFFF) * 16 + c2];
                float4 wa = wl4[((pa.x >> 17) & 15) * 16 + c2];
                float4 wb = wl4[((pb.x >> 17) & 15) * 16 + c2];
                float4 wc = wl4[((pc.x >> 17) & 15) * 16 + c2];
                float4 wd = wl4[((pd.x >> 17) & 15) * 16 + c2];
                float sa = __int_as_float(pa.y);
                float sb = __int_as_float(pb.y);
                float sc = __int_as_float(pc.y);
                float sd = __int_as_float(pd.y);
                v2f wa01 = {wa.x, wa.y}, wa23 = {wa.z, wa.w};
                v2f wb01 = {wb.x, wb.y}, wb23 = {wb.z, wb.w};
                v2f wc01 = {wc.x, wc.y}, wc23 = {wc.z, wc.w};
                v2f wd01 = {wd.x, wd.y}, wd23 = {wd.z, wd.w};
                a01 += bfpair(qa.x) * (wa01 * sa);  a23 += bfpair(qa.y) * (wa23 * sa);
                a01 += bfpair(qb.x) * (wb01 * sb);  a23 += bfpair(qb.y) * (wb23 * sb);
                a01 += bfpair(qc.x) * (wc01 * sc);  a23 += bfpair(qc.y) * (wc23 * sc);
                a01 += bfpair(qd.x) * (wd01 * sd);  a23 += bfpair(qd.y) * (wd23 * sd);
            }
            for (; i + 7 < e; i += 8) {
                int2 pa = sbuf[i + g];
                int2 pb = sbuf[i + 4 + g];
                uint2 qa = cur64[(size_t)(pa.x & 0x1FFFF) * 16 + c2];
                uint2 qb = cur64[(size_t)(pb.x & 0x1FFFF) * 16 + c2];
                float4 wa = wl4[((pa.x >> 17) & 15) * 16 + c2];
                float4 wb = wl4[((pb.x >> 17) & 15) * 16 + c2];
                float sa = __int_as_float(pa.y);
                float sb = __int_as_float(pb.y);
                v2f wa01 = {wa.x, wa.y}, wa23 = {wa.z, wa.w};
                v2f wb01 = {wb.x, wb.y}, wb23 = {wb.z, wb.w};
                a01 += bfpair(qa.x) * (wa01 * sa);  a23 += bfpair(qa.y) * (wa23 * sa);
                a01 += bfpair(qb.x) * (wb01 * sb);  a23 += bfpair(qb.y) * (wb23 * sb);
            }
            for (; i < e; i += 4) {
                int idx = i + g;
                bool vld = idx < e;
                int2 p = sbuf[vld ? idx : i];
                uint2 q = cur64[(size_t)(p.x & 0x1FFFF) * 16 + c2];
                float4 wv = wl4[((p.x >> 17) & 15) * 16 + c2];
                float sv = vld ? __int_as_float(p.y) : 0.f;
                v2f wv01 = {wv.x, wv.y}, wv23 = {wv.z, wv.w};
                a01 += bfpair(q.x) * (wv01 * sv);  a23 += bfpair(q.y) * (wv23 * sv);
            }
        }

        // merge the 4 edge-groups, L2-normalize, res = emb + y
        float x0 = a01.x, x1 = a01.y, x2 = a23.x, x3 = a23.y;
        x0 += __shfl_xor(x0, 16, 64); x0 += __shfl_xor(x0, 32, 64);
        x1 += __shfl_xor(x1, 16, 64); x1 += __shfl_xor(x1, 32, 64);
        x2 += __shfl_xor(x2, 16, 64); x2 += __shfl_xor(x2, 32, 64);
        x3 += __shfl_xor(x3, 16, 64); x3 += __shfl_xor(x3, 32, 64);
        float ss = x0 * x0 + x1 * x1 + x2 * x2 + x3 * x3;
        #pragma unroll
        for (int o = 8; o; o >>= 1) ss += __shfl_xor(ss, o, 64);
        float inv = 1.f / fmaxf(sqrtf(ss), 1e-12f);
        float y0 = x0 * inv, y1 = x1 * inv, y2 = x2 * inv, y3 = x3 * inv;
        if (g == 0) {    // lanes 0-15 hold the complete row; 16B stores
            if (is_user) {
                int grow = b * RPB + row;
                if (grow < N_USERS) {
                    float4 v = src_u[(size_t)grow * 16 + c2];
                    v.x += y0; v.y += y1; v.z += y2; v.w += y3;
                    ((float4*)res_u)[(size_t)grow * 16 + c2] = v;
                }
            } else {
                int grow = eb * RPB + row;
                if (grow < N_ENTITIES) {
                    uint2 pk;
                    pk.x = (unsigned)f2bf(y0) | ((unsigned)f2bf(y1) << 16);
                    pk.y = (unsigned)f2bf(y2) | ((unsigned)f2bf(y3) << 16);
                    ((uint2*)nxt)[(size_t)grow * 16 + c2] = pk;
                    float4 v = src_e[(size_t)grow * 16 + c2];
                    v.x += y0; v.y += y1; v.z += y2; v.w += y3;
                    ((float4*)res_e)[(size_t)grow * 16 + c2] = v;
                }
            }
        }
    }
}

// ---------------------------------------------------------------------------
// Aggregation hop 2 (v9): half-bucket blocks (256 thr = 4 waves), 16-edge
// unroll, 16 lanes/edge, uint2 = 4 packed bf16 channels, packed-f32 math.
// Epilogue: merge 4 groups, L2-normalize, res += y, bf16 next-state.
// ---------------------------------------------------------------------------
__global__ void __launch_bounds__(256)
agg_kernel(const uint2* __restrict__ cur64,    // bf16 quads, 16 uint2/row
           const float* __restrict__ weight,
           const int2* __restrict__ binAll, const int* __restrict__ rowptr,
           unsigned short* __restrict__ nxt,
           const float4* __restrict__ src_e, const float4* __restrict__ src_u,
           float* __restrict__ res_e, float* __restrict__ res_u) {
    __shared__ float4 wl4[N_RELATIONS * 16];   // 4 KB
    __shared__ int    srp[33];

    const int hb = blockIdx.x;       // half-bucket
    const int b = hb >> 1;
    const int half = hb & 1;
    const int t = threadIdx.x;
    const int w = t >> 6;            // wave 0..3
    const int lane = t & 63;
    const int g = lane >> 4;         // edge-group 0..3
    const int c2 = lane & 15;        // uint2 index within row (4 channels)
    const bool is_user = (b < NB_U);
    const int eb = b - NB_U;

    if (!is_user)
        for (int i = t; i < N_RELATIONS * 16; i += 256)
            wl4[i] = ((const float4*)weight)[i];
    if (t < 33) srp[t] = rowptr[b * 65 + half * 32 + t];
    __syncthreads();

    #pragma unroll
    for (int rr = 0; rr < 8; ++rr) {
        const int row_l = (w << 3) + rr;               // 0..31 within half
        const int s = srp[row_l], e = srp[row_l + 1];
        v2f a01 = {0.f, 0.f}, a23 = {0.f, 0.f};
        int i = s;
        if (is_user) {
            for (; i + 15 < e; i += 16) {
                int2 pa = binAll[i + g];
                int2 pb = binAll[i + 4 + g];
                int2 pc = binAll[i + 8 + g];
                int2 pd = binAll[i + 12 + g];
                uint2 qa = cur64[(size_t)(pa.x & 0x1FFFF) * 16 + c2];
                uint2 qb = cur64[(size_t)(pb.x & 0x1FFFF) * 16 + c2];
                uint2 qc = cur64[(size_t)(pc.x & 0x1FFFF) * 16 + c2];
                uint2 qd = cur64[(size_t)(pd.x & 0x1FFFF) * 16 + c2];
                float sa = __int_as_float(pa.y);
                float sb = __int_as_float(pb.y);
                float sc = __int_as_float(pc.y);
                float sd = __int_as_float(pd.y);
                a01 += bfpair(qa.x) * sa;  a23 += bfpair(qa.y) * sa;
                a01 += bfpair(qb.x) * sb;  a23 += bfpair(qb.y) * sb;
                a01 += bfpair(qc.x) * sc;  a23 += bfpair(qc.y) * sc;
                a01 += bfpair(qd.x) * sd;  a23 += bfpair(qd.y) * sd;
            }
            for (; i + 7 < e; i += 8) {
                int2 pa = binAll[i + g];
                int2 pb = binAll[i + 4 + g];
                uint2 qa = cur64[(size_t)(pa.x & 0x1FFFF) * 16 + c2];
                uint2 qb = cur64[(size_t)(pb.x & 0x1FFFF) * 16 + c2];
                float sa = __int_as_float(pa.y);
                float sb = __int_as_float(pb.y);
                a01 += bfpair(qa.x) * sa;  a23 += bfpair(qa.y) * sa;
                a01 += bfpair(qb.x) * sb;  a23 += bfpair(qb.y) * sb;
            }
            for (; i < e; i += 4) {          // masked 4-edge tail
                int idx = i + g;
                bool vld = idx < e;
                int2 p = binAll[vld ? idx : i];
                uint2 q = cur64[(size_t)(p.x & 0x1FFFF) * 16 + c2];
                float sv = vld ? __int_as_float(p.y) : 0.f;
                a01 += bfpair(q.x) * sv;  a23 += bfpair(q.y) * sv;
            }
        } else {
            for (; i + 15 < e; i += 16) {
                int2 pa = binAll[i + g];
                int2 pb = binAll[i + 4 + g];
                int2 pc = binAll[i + 8 + g];
                int2 pd = binAll[i + 12 + g];
                uint2 qa = cur64[(size_t)(pa.x & 0x1FFFF) * 16 + c2];
                uint2 qb = cur64[(size_t)(pb.x & 0x1FFFF) * 16 + c2];
                uint2 qc = cur64[(size_t)(pc.x & 0x1FFFF) * 16 + c2];
                uint2 qd = cur64[(size_t)(pd.x & 0x1FFFF) * 16 + c2];
                float4 wa = wl4[((pa.x >> 17) & 15) * 16 + c2];
                float4 wb = wl4[((pb.x >> 17) & 15) * 16 + c2];
                float4 wc = wl4[((pc.x >> 17) & 15) * 16 + c2];
                float4 wd = wl4[((pd.x >> 17) & 15) * 16 + c2];
                float sa = __int_as_float(pa.y);
                float sb = __int_as_float(pb.y);
                float sc = __int_as_float(pc.y);
                float sd = __int_as_float(pd.y);
                v2f wa01 = {wa.x, wa.y}, wa23 = {wa.z, wa.w};
                v2f wb01 = {wb.x, wb.y}, wb23 = {wb.z, wb.w};
                v2f wc01 = {wc.x, wc.y}, wc23 = {wc.z, wc.w};
                v2f wd01 = {wd.x, wd.y}, wd23 = {wd.z, wd.w};
                a01 += bfpair(qa.x) * (wa01 * sa);  a23 += bfpair(qa.y) * (wa23 * sa);
                a01 += bfpair(qb.x) * (wb01 * sb);  a23 += bfpair(qb.y) * (wb23 * sb);
                a01 += bfpair(qc.x) * (wc01 * sc);  a23 += bfpair(qc.y) * (wc23 * sc);
                a01 += bfpair(qd.x) * (wd01 * sd);  a23 += bfpair(qd.y) * (wd23 * sd);
            }
            for (; i + 7 < e; i += 8) {
                int2 pa = binAll[i + g];
                int2 pb = binAll[i + 4 + g];
                uint2 qa = cur64[(size_t)(pa.x & 0x1FFFF) * 16 + c2];
                uint2 qb = cur64[(size_t)(pb.x & 0x1FFFF) * 16 + c2];
                float4 wa = wl4[((pa.x >> 17) & 15) * 16 + c2];
                float4 wb = wl4[((pb.x >> 17) & 15) * 16 + c2];
                float sa = __int_as_float(pa.y);
                float sb = __int_as_float(pb.y);
                v2f wa01 = {wa.x, wa.y}, wa23 = {wa.z, wa.w};
                v2f wb01 = {wb.x, wb.y}, wb23 = {wb.z, wb.w};
                a01 += bfpair(qa.x) * (wa01 * sa);  a23 += bfpair(qa.y) * (wa23 * sa);
                a01 += bfpair(qb.x) * (wb01 * sb);  a23 += bfpair(qb.y) * (wb23 * sb);
            }
            for (; i < e; i += 4) {
                int idx = i + g;
                bool vld = idx < e;
                int2 p = binAll[vld ? idx : i];
                uint2 q = cur64[(size_t)(p.x & 0x1FFFF) * 16 + c2];
                float4 wv = wl4[((p.x >> 17) & 15) * 16 + c2];
                float sv = vld ? __int_as_float(p.y) : 0.f;
                v2f wv01 = {wv.x, wv.y}, wv23 = {wv.z, wv.w};
                a01 += bfpair(q.x) * (wv01 * sv);  a23 += bfpair(q.y) * (wv23 * sv);
            }
        }

        // merge the 4 edge-groups
        float x0 = a01.x, x1 = a01.y, x2 = a23.x, x3 = a23.y;
        x0 += __shfl_xor(x0, 16, 64); x0 += __shfl_xor(x0, 32, 64);
        x1 += __shfl_xor(x1, 16, 64); x1 += __shfl_xor(x1, 32, 64);
        x2 += __shfl_xor(x2, 16, 64); x2 += __shfl_xor(x2, 32, 64);
        x3 += __shfl_xor(x3, 16, 64); x3 += __shfl_xor(x3, 32, 64);
        float ss = x0 * x0 + x1 * x1 + x2 * x2 + x3 * x3;
        #pragma unroll
        for (int o = 8; o; o >>= 1) ss += __shfl_xor(ss, o, 64);
        float inv = 1.f / fmaxf(sqrtf(ss), 1e-12f);
        float y0 = x0 * inv, y1 = x1 * inv, y2 = x2 * inv, y3 = x3 * inv;
        if (g == 0) {    // lanes 0-15 hold the complete row; 16B stores
            const int lrow = half * 32 + row_l;
            if (is_user) {
                int grow = b * RPB + lrow;
                if (grow < N_USERS) {
                    float4 v = src_u[(size_t)grow * 16 + c2];
                    v.x += y0; v.y += y1; v.z += y2; v.w += y3;
                    ((float4*)res_u)[(size_t)grow * 16 + c2] = v;
                }
            } else {
                int grow = eb * RPB + lrow;
                if (grow < N_ENTITIES) {
                    uint2 pk;
                    pk.x = (unsigned)f2bf(y0) | ((unsigned)f2bf(y1) << 16);
                    pk.y = (unsigned)f2bf(y2) | ((unsigned)f2bf(y3) << 16);
                    ((uint2*)nxt)[(size_t)grow * 16 + c2] = pk;
                    float4 v = src_e[(size_t)grow * 16 + c2];
                    v.x += y0; v.y += y1; v.z += y2; v.w += y3;
                    ((float4*)res_e)[(size_t)grow * 16 + c2] = v;
                }
            }
        }
    }
}

extern "C" void kernel_launch(void* const* d_in, const int* in_sizes, int n_in,
                              void* d_out, int out_size, void* d_ws, size_t ws_size,
                              hipStream_t stream) {
    const float* user_emb   = (const float*)d_in[0];
    const float* entity_emb = (const float*)d_in[1];
    const float* weight     = (const float*)d_in[2];
    const float* mask       = (const float*)d_in[3];
    const float* ivals      = (const float*)d_in[4];
    const int*   edge_head  = (const int*)d_in[5];
    const int*   edge_tail  = (const int*)d_in[6];
    const int*   edge_type  = (const int*)d_in[7];
    const int*   irows      = (const int*)d_in[8];
    const int*   icols      = (const int*)d_in[9];

    float* out_entity = (float*)d_out;
    float* out_user   = (float*)d_out + (size_t)N_ENTITIES * CH;

    // ---- d_out doubles as coarse-bin scratch until sortagg rewrites it ----
    int2* cbE   = (int2*)d_out;                          // 49*67072*8 = 26.29 MB
    int2* cbU_d = cbE + (size_t)NCE * CAPC_E;            // 14*104448*8 = 11.70 MB

    // ---- workspace layout (~81.0 MB) ----
    unsigned short* curA = (unsigned short*)d_ws;                    // 12.8 MB
    unsigned short* curB = curA + (size_t)N_ENTITIES * CH;           // 12.8 MB
    int2* binAll = (int2*)(curB + (size_t)N_ENTITIES * CH);          // 45.6 MB
    int2* cbU_w  = binAll + (size_t)(N_EDGES + NNZ);                 // 9.19 MB
    int*  fineCnt  = (int*)(cbU_w + (size_t)(NCU - NCU_DOUT) * CAPC_U);
    int*  cCurE    = fineCnt + NBUCKETS;                             // 49
    int*  cCurU    = cCurE + NCE;                                    // 25
    int*  fineBase = cCurU + NCU;                                    // 2345
    int*  fineCur  = fineBase + NBUCKETS;                            // 2345
    int*  rowptr   = fineCur + NBUCKETS;                             // 2345*65

    hipMemsetAsync(fineCnt, 0, (size_t)(NBUCKETS + NCE + NCU) * sizeof(int), stream);

    // ---- pass A: coarse partition + exact fine counts + bf16 pack ----
    passA_kernel<<<PA_KG + PA_U + PACK_BLOCKS, 1024, 0, stream>>>(
        edge_head, edge_tail, edge_type, mask, irows, icols, ivals,
        (const float4*)entity_emb, (ushort4*)curA,
        fineCnt, cCurE, cCurU, cbE, cbU_d, cbU_w);

    // ---- exclusive scan -> exact CSR bases + pass-B cursors ----
    scan_kernel<<<1, 512, 0, stream>>>(fineCnt, fineBase, fineCur);

    // ---- pass B: fine partition into exact CSR (per-block reservations) ----
    passB_kernel<<<NCE * SE + NCU * SU, 1024, 0, stream>>>(
        cCurE, cCurU, cbE, cbU_d, cbU_w, fineCur, binAll);

    // ---- fused sort + hop 1 (res = emb + y) ----
    sortagg_kernel<<<NBUCKETS, 512, 0, stream>>>(
        binAll, fineCnt, fineBase, rowptr,
        (const uint2*)curA, weight, curB,
        (const float4*)entity_emb, (const float4*)user_emb,
        out_entity, out_user);

    // ---- hop 2 (res += y) ----
    agg_kernel<<<2 * NBUCKETS, 256, 0, stream>>>(
        (const uint2*)curB, weight, binAll, rowptr, curA,
        (const float4*)out_entity, (const float4*)out_user,
        out_entity, out_user);
}

// Round 13
// 451.919 us; speedup vs baseline: 1.0106x; 1.0106x over previous
//
#include <hip/hip_runtime.h>

#define N_USERS 50000
#define N_ENTITIES 100000
#define N_RELATIONS 16
#define N_EDGES 3200000
#define NNZ 2500000
#define CH 64

#define RPB 64
#define NB_E 1563                 // ceil(N_ENTITIES/64) fine buckets
#define NB_U 782                  // ceil(N_USERS/64)
#define NBUCKETS (NB_E + NB_U)    // 2345
#define STAGE 3840                // sort LDS staging capacity (max bucket ~3500)

#define NCE 49                    // entity coarse buckets (2048 rows each)
#define NCU 25                    // user coarse buckets (2048 rows each)
#define CAPC_E 67072              // mean 65306, +~7 sigma
#define CAPC_U 104448             // mean 100000, +~14 sigma
#define NCU_DOUT 14               // user coarse buckets hosted in d_out scratch

#define PA_KG 256                 // pass-A KG blocks (r11 proven config)
#define PA_U  192                 // pass-A user blocks
#define PACK_BLOCKS 1563          // bf16-pack blocks appended to pass-A grid
#define SE 10                     // pass-B sub-blocks per entity coarse bucket
#define SU 16                     // pass-B sub-blocks per user coarse bucket

typedef float v2f __attribute__((ext_vector_type(2)));

__device__ __forceinline__ unsigned short f2bf(float f) {
    unsigned u = __float_as_uint(f);
    u += 0x7FFF + ((u >> 16) & 1);   // round-to-nearest-even
    return (unsigned short)(u >> 16);
}

// unpack a packed bf16 pair into {lo, hi} as f32x2 (2 VALU ops)
__device__ __forceinline__ v2f bfpair(unsigned q) {
    v2f r;
    r.x = __uint_as_float(q << 16);
    r.y = __uint_as_float(q & 0xFFFF0000u);
    return r;
}

__device__ __forceinline__ int wave_incl_scan(int v, int lane) {
    int s = v;
    #pragma unroll
    for (int d = 1; d < 64; d <<= 1) {
        int x = __shfl_up(s, d, 64);
        if (lane >= d) s += x;
    }
    return s;
}

// ---------------------------------------------------------------------------
// Pass A: coarse partition (2048-row buckets) with per-block contiguous
// reservations (~1x write amp) + EXACT per-fine-bucket counts (LDS
// histogram) + bf16 pack of the entity table. Payload: fine-within-coarse
// in bits 27-31; low fields unchanged.
// ---------------------------------------------------------------------------
__global__ void __launch_bounds__(1024)
passA_kernel(const int* __restrict__ head, const int* __restrict__ tail,
             const int* __restrict__ type, const float* __restrict__ maskp,
             const int* __restrict__ irows, const int* __restrict__ icols,
             const float* __restrict__ ivals,
             const float4* __restrict__ entity_emb, ushort4* __restrict__ cur_bf,
             int* __restrict__ fineCnt, int* __restrict__ cCurE,
             int* __restrict__ cCurU,
             int2* __restrict__ cbE, int2* __restrict__ cbU_d,
             int2* __restrict__ cbU_w) {
    __shared__ int histF[NB_E];
    __shared__ int histC[64];
    __shared__ int lbase[64];
    __shared__ int2* utab[NCU];
    const int blk = blockIdx.x;
    const int t = threadIdx.x;

    if (blk >= PA_KG + PA_U) {
        // ---- bf16 pack: curA = bf16(entity_emb) ----
        const int ne4 = N_ENTITIES * CH / 4;
        int i = (blk - PA_KG - PA_U) * 1024 + t;
        if (i < ne4) {
            float4 v = entity_emb[i];
            ushort4 bq;
            bq.x = f2bf(v.x); bq.y = f2bf(v.y); bq.z = f2bf(v.z); bq.w = f2bf(v.w);
            cur_bf[i] = bq;
        }
        return;
    }

    if (blk < PA_KG) {
        // ---- KG edges ----
        for (int i = t; i < NB_E; i += 1024) histF[i] = 0;
        if (t < NCE) histC[t] = 0;
        __syncthreads();
        const int chunk = (N_EDGES + PA_KG - 1) / PA_KG;
        int base = blk * chunk, lim = min(base + chunk, N_EDGES);
        for (int i = base + t; i < lim; i += 1024) {
            int h = head[i];
            atomicAdd(&histF[h >> 6], 1);
            atomicAdd(&histC[h >> 11], 1);
        }
        __syncthreads();
        for (int i = t; i < NB_E; i += 1024)
            if (histF[i]) atomicAdd(&fineCnt[NB_U + i], histF[i]);
        if (t < NCE) {
            int c = histC[t];
            lbase[t] = c ? atomicAdd(&cCurE[t], c) : 0;
            histC[t] = 0;
        }
        __syncthreads();
        int i = base + t;
        for (; i + 3072 < lim; i += 4096) {
            int i0 = i, i1 = i + 1024, i2 = i + 2048, i3 = i + 3072;
            int h0 = head[i0], h1 = head[i1], h2 = head[i2], h3 = head[i3];
            int x0 = tail[i0] | ((type[i0] - 1) << 17) | ((h0 & 63) << 21) | (((h0 >> 6) & 31) << 27);
            int x1 = tail[i1] | ((type[i1] - 1) << 17) | ((h1 & 63) << 21) | (((h1 >> 6) & 31) << 27);
            int x2 = tail[i2] | ((type[i2] - 1) << 17) | ((h2 & 63) << 21) | (((h2 >> 6) & 31) << 27);
            int x3 = tail[i3] | ((type[i3] - 1) << 17) | ((h3 & 63) << 21) | (((h3 >> 6) & 31) << 27);
            float m0 = maskp[i0], m1 = maskp[i1], m2 = maskp[i2], m3 = maskp[i3];
            int c0 = h0 >> 11, c1 = h1 >> 11, c2 = h2 >> 11, c3 = h3 >> 11;
            int l0 = lbase[c0] + atomicAdd(&histC[c0], 1);
            int l1 = lbase[c1] + atomicAdd(&histC[c1], 1);
            int l2 = lbase[c2] + atomicAdd(&histC[c2], 1);
            int l3 = lbase[c3] + atomicAdd(&histC[c3], 1);
            if (l0 < CAPC_E) cbE[(size_t)c0 * CAPC_E + l0] = make_int2(x0, __float_as_int(m0));
            if (l1 < CAPC_E) cbE[(size_t)c1 * CAPC_E + l1] = make_int2(x1, __float_as_int(m1));
            if (l2 < CAPC_E) cbE[(size_t)c2 * CAPC_E + l2] = make_int2(x2, __float_as_int(m2));
            if (l3 < CAPC_E) cbE[(size_t)c3 * CAPC_E + l3] = make_int2(x3, __float_as_int(m3));
        }
        for (; i < lim; i += 1024) {
            int h = head[i];
            int x = tail[i] | ((type[i] - 1) << 17) | ((h & 63) << 21) | (((h >> 6) & 31) << 27);
            int c = h >> 11;
            int loc = lbase[c] + atomicAdd(&histC[c], 1);
            if (loc < CAPC_E)
                cbE[(size_t)c * CAPC_E + loc] = make_int2(x, __float_as_int(maskp[i]));
        }
    } else {
        // ---- user interactions ----
        if (t < NCU)
            utab[t] = (t < NCU_DOUT) ? (cbU_d + (size_t)t * CAPC_U)
                                     : (cbU_w + (size_t)(t - NCU_DOUT) * CAPC_U);
        for (int i = t; i < NB_U; i += 1024) histF[i] = 0;
        if (t < NCU) histC[t] = 0;
        __syncthreads();
        const int ub = blk - PA_KG;
        const int chunk = (NNZ + PA_U - 1) / PA_U;
        int base = ub * chunk, lim = min(base + chunk, NNZ);
        for (int i = base + t; i < lim; i += 1024) {
            int r = irows[i];
            atomicAdd(&histF[r >> 6], 1);
            atomicAdd(&histC[r >> 11], 1);
        }
        __syncthreads();
        for (int i = t; i < NB_U; i += 1024)
            if (histF[i]) atomicAdd(&fineCnt[i], histF[i]);
        if (t < NCU) {
            int c = histC[t];
            lbase[t] = c ? atomicAdd(&cCurU[t], c) : 0;
            histC[t] = 0;
        }
        __syncthreads();
        int i = base + t;
        for (; i + 3072 < lim; i += 4096) {
            int i0 = i, i1 = i + 1024, i2 = i + 2048, i3 = i + 3072;
            int r0 = irows[i0], r1 = irows[i1], r2 = irows[i2], r3 = irows[i3];
            int x0 = icols[i0] | ((r0 & 63) << 17) | (((r0 >> 6) & 31) << 27);
            int x1 = icols[i1] | ((r1 & 63) << 17) | (((r1 >> 6) & 31) << 27);
            int x2 = icols[i2] | ((r2 & 63) << 17) | (((r2 >> 6) & 31) << 27);
            int x3 = icols[i3] | ((r3 & 63) << 17) | (((r3 >> 6) & 31) << 27);
            float v0 = ivals[i0], v1 = ivals[i1], v2 = ivals[i2], v3 = ivals[i3];
            int c0 = r0 >> 11, c1 = r1 >> 11, c2 = r2 >> 11, c3 = r3 >> 11;
            int l0 = lbase[c0] + atomicAdd(&histC[c0], 1);
            int l1 = lbase[c1] + atomicAdd(&histC[c1], 1);
            int l2 = lbase[c2] + atomicAdd(&histC[c2], 1);
            int l3 = lbase[c3] + atomicAdd(&histC[c3], 1);
            if (l0 < CAPC_U) utab[c0][l0] = make_int2(x0, __float_as_int(v0));
            if (l1 < CAPC_U) utab[c1][l1] = make_int2(x1, __float_as_int(v1));
            if (l2 < CAPC_U) utab[c2][l2] = make_int2(x2, __float_as_int(v2));
            if (l3 < CAPC_U) utab[c3][l3] = make_int2(x3, __float_as_int(v3));
        }
        for (; i < lim; i += 1024) {
            int r = irows[i];
            int x = icols[i] | ((r & 63) << 17) | (((r >> 6) & 31) << 27);
            int c = r >> 11;
            int loc = lbase[c] + atomicAdd(&histC[c], 1);
            if (loc < CAPC_U) utab[c][loc] = make_int2(x, __float_as_int(ivals[i]));
        }
    }
}

// ---------------------------------------------------------------------------
// Scan: exclusive prefix over the 2345 exact fine-bucket counts ->
// fineBase (CSR bases) and fineCur (pass-B cursors).
// ---------------------------------------------------------------------------
__global__ void __launch_bounds__(512)
scan_kernel(const int* __restrict__ fineCnt, int* __restrict__ fineBase,
            int* __restrict__ fineCur) {
    __shared__ int wsums[8];
    __shared__ int carry_s;
    const int t = threadIdx.x, w = t >> 6, lane = t & 63;
    if (t == 0) carry_s = 0;
    __syncthreads();
    for (int base = 0; base < NBUCKETS; base += 512) {
        int i = base + t;
        int v = (i < NBUCKETS) ? fineCnt[i] : 0;
        int s = wave_incl_scan(v, lane);
        if (lane == 63) wsums[w] = s;
        __syncthreads();
        int carry = carry_s;
        if (w == 0) {
            int ws = (lane < 8) ? wsums[lane] : 0;
            int ss = wave_incl_scan(ws, lane);
            if (lane < 8) wsums[lane] = ss - ws;
        }
        __syncthreads();
        int excl = s - v + wsums[w] + carry;
        if (i < NBUCKETS) { fineBase[i] = excl; fineCur[i] = excl; }
        __syncthreads();
        if (t == 511) carry_s = excl + v;
        __syncthreads();
    }
}

// ---------------------------------------------------------------------------
// Pass B: fine partition with PER-BLOCK CONTIGUOUS RESERVATIONS (the rule:
// never per-edge global cursors — rounds 3/7 showed 7x write amplification).
// ---------------------------------------------------------------------------
__global__ void __launch_bounds__(1024)
passB_kernel(const int* __restrict__ cCurE, const int* __restrict__ cCurU,
             const int2* __restrict__ cbE, const int2* __restrict__ cbU_d,
             const int2* __restrict__ cbU_w,
             int* __restrict__ fineCur, int2* __restrict__ binAll) {
    __shared__ int h32[32];
    __shared__ int lb[32];
    const int blk = blockIdx.x, t = threadIdx.x;
    const int2* __restrict__ src;
    int cnt, sub, S, fid0;
    if (blk < NCE * SE) {
        int c = blk / SE; sub = blk % SE; S = SE;
        cnt = min(cCurE[c], CAPC_E);
        src = cbE + (size_t)c * CAPC_E;
        fid0 = NB_U + c * 32;
    } else {
        int c = (blk - NCE * SE) / SU; sub = (blk - NCE * SE) % SU; S = SU;
        cnt = min(cCurU[c], CAPC_U);
        src = (c < NCU_DOUT) ? cbU_d + (size_t)c * CAPC_U
                             : cbU_w + (size_t)(c - NCU_DOUT) * CAPC_U;
        fid0 = c * 32;
    }
    int len = (cnt + S - 1) / S;
    int b0 = sub * len, b1 = min(b0 + len, cnt);
    if (t < 32) h32[t] = 0;
    __syncthreads();
    for (int i = b0 + t; i < b1; i += 1024)
        atomicAdd(&h32[(src[i].x >> 27) & 31], 1);
    __syncthreads();
    if (t < 32) {
        int c2 = h32[t];
        lb[t] = c2 ? atomicAdd(&fineCur[fid0 + t], c2) : 0;
        h32[t] = 0;
    }
    __syncthreads();
    int i = b0 + t;
    for (; i + 3072 < b1; i += 4096) {
        int2 e0 = src[i], e1 = src[i + 1024], e2 = src[i + 2048], e3 = src[i + 3072];
        int f0 = (e0.x >> 27) & 31, f1 = (e1.x >> 27) & 31;
        int f2 = (e2.x >> 27) & 31, f3 = (e3.x >> 27) & 31;
        int l0 = lb[f0] + atomicAdd(&h32[f0], 1);
        int l1 = lb[f1] + atomicAdd(&h32[f1], 1);
        int l2 = lb[f2] + atomicAdd(&h32[f2], 1);
        int l3 = lb[f3] + atomicAdd(&h32[f3], 1);
        binAll[l0] = e0; binAll[l1] = e1; binAll[l2] = e2; binAll[l3] = e3;
    }
    for (; i < b1; i += 1024) {
        int2 e = src[i];
        int f = (e.x >> 27) & 31;
        binAll[lb[f] + atomicAdd(&h32[f], 1)] = e;
    }
}

// ---------------------------------------------------------------------------
// Fused sort + hop-1 aggregation: one block (512 thr = 8 waves) per bucket.
// Phase 1: load the whole bucket into REGISTERS (8 int2/thread) — binAll
// read exactly once. Phase 2: histogram + scan + scatter into the LDS sort
// buffer. Phase 3: write sorted bucket back (hop 2 needs it) + rowptr.
// Phase 4: aggregate straight from LDS, packed-math inner loop,
// res = emb + y epilogue.
// ---------------------------------------------------------------------------
__global__ void __launch_bounds__(512)
sortagg_kernel(int2* __restrict__ binAll, const int* __restrict__ fineCnt,
               const int* __restrict__ fineBase, int* __restrict__ rowptr,
               const uint2* __restrict__ cur64, const float* __restrict__ weight,
               unsigned short* __restrict__ nxt,
               const float4* __restrict__ src_e, const float4* __restrict__ src_u,
               float* __restrict__ res_e, float* __restrict__ res_u) {
    __shared__ int2   sbuf[STAGE];             // 30720 B (sorted bucket)
    __shared__ float4 wl4[N_RELATIONS * 16];   // 4 KB
    __shared__ int    hist[RPB];
    __shared__ int    offs[RPB + 1];

    const int b = blockIdx.x;
    const int t = threadIdx.x;
    const bool is_user = (b < NB_U);
    const int eb = b - NB_U;
    const int base = fineBase[b];
    int2* __restrict__ bin = binAll + base;
    const int cnt = min(fineCnt[b], STAGE);
    const int rsh = is_user ? 17 : 21;

    // ---- phase 1: bucket -> registers, histogram ----
    int2 ebuf[8];
    if (t < RPB) hist[t] = 0;
    #pragma unroll
    for (int j = 0; j < 8; ++j) {
        int idx = t + (j << 9);
        if (idx < cnt) ebuf[j] = bin[idx];
    }
    if (!is_user)
        for (int i = t; i < N_RELATIONS * 16; i += 512)
            wl4[i] = ((const float4*)weight)[i];
    __syncthreads();
    #pragma unroll
    for (int j = 0; j < 8; ++j) {
        int idx = t + (j << 9);
        if (idx < cnt) atomicAdd(&hist[(ebuf[j].x >> rsh) & 63], 1);
    }
    __syncthreads();
    // ---- phase 2: scan + scatter into LDS ----
    if (t < 64) {
        int v = hist[t];
        int s = wave_incl_scan(v, t);
        offs[t] = s - v;
        if (t == 63) offs[64] = s;
    }
    __syncthreads();
    if (t < RPB) hist[t] = 0;        // becomes cursor
    __syncthreads();
    #pragma unroll
    for (int j = 0; j < 8; ++j) {
        int idx = t + (j << 9);
        if (idx < cnt) {
            int r = (ebuf[j].x >> rsh) & 63;
            int k = atomicAdd(&hist[r], 1);
            sbuf[offs[r] + k] = ebuf[j];
        }
    }
    __syncthreads();
    // ---- phase 3: sorted writeback (for hop 2) + rowptr ----
    for (int i = t; i < cnt; i += 512) bin[i] = sbuf[i];
    if (t <= 64) rowptr[b * 65 + t] = base + offs[t];

    // ---- phase 4: aggregation from LDS ----
    const int w = t >> 6;            // wave 0..7
    const int lane = t & 63;
    const int g = lane >> 4;         // edge-group 0..3
    const int c2 = lane & 15;        // uint2 index within row (4 channels)

    #pragma unroll
    for (int rr = 0; rr < 8; ++rr) {
        const int row = (w << 3) + rr;
        const int s = offs[row], e = offs[row + 1];   // LOCAL sbuf indices
        v2f a01 = {0.f, 0.f}, a23 = {0.f, 0.f};
        int i = s;
        if (is_user) {
            for (; i + 15 < e; i += 16) {
                int2 pa = sbuf[i + g];
                int2 pb = sbuf[i + 4 + g];
                int2 pc = sbuf[i + 8 + g];
                int2 pd = sbuf[i + 12 + g];
                uint2 qa = cur64[(size_t)(pa.x & 0x1FFFF) * 16 + c2];
                uint2 qb = cur64[(size_t)(pb.x & 0x1FFFF) * 16 + c2];
                uint2 qc = cur64[(size_t)(pc.x & 0x1FFFF) * 16 + c2];
                uint2 qd = cur64[(size_t)(pd.x & 0x1FFFF) * 16 + c2];
                float sa = __int_as_float(pa.y);
                float sb = __int_as_float(pb.y);
                float sc = __int_as_float(pc.y);
                float sd = __int_as_float(pd.y);
                a01 += bfpair(qa.x) * sa;  a23 += bfpair(qa.y) * sa;
                a01 += bfpair(qb.x) * sb;  a23 += bfpair(qb.y) * sb;
                a01 += bfpair(qc.x) * sc;  a23 += bfpair(qc.y) * sc;
                a01 += bfpair(qd.x) * sd;  a23 += bfpair(qd.y) * sd;
            }
            for (; i + 7 < e; i += 8) {
                int2 pa = sbuf[i + g];
                int2 pb = sbuf[i + 4 + g];
                uint2 qa = cur64[(size_t)(pa.x & 0x1FFFF) * 16 + c2];
                uint2 qb = cur64[(size_t)(pb.x & 0x1FFFF) * 16 + c2];
                float sa = __int_as_float(pa.y);
                float sb = __int_as_float(pb.y);
                a01 += bfpair(qa.x) * sa;  a23 += bfpair(qa.y) * sa;
                a01 += bfpair(qb.x) * sb;  a23 += bfpair(qb.y) * sb;
            }
            for (; i < e; i += 4) {
                int idx = i + g;
                bool vld = idx < e;
                int2 p = sbuf[vld ? idx : i];
                uint2 q = cur64[(size_t)(p.x & 0x1FFFF) * 16 + c2];
                float sv = vld ? __int_as_float(p.y) : 0.f;
                a01 += bfpair(q.x) * sv;  a23 += bfpair(q.y) * sv;
            }
        } else {
            for (; i + 15 < e; i += 16) {
                int2 pa = sbuf[i + g];
                int2 pb = sbuf[i + 4 + g];
                int2 pc = sbuf[i + 8 + g];
                int2 pd = sbuf[i + 12 + g];
                uint2 qa = cur64[(size_t)(pa.x & 0x1FFFF) * 16 + c2];
                uint2 qb = cur64[(size_t)(pb.x & 0x1FFFF) * 16 + c2];
                uint2 qc = cur64[(size_t)(pc.x & 0x1FFFF) * 16 + c2];
                uint2 qd = cur64[(size_t)(pd.x & 0x1FFFF) * 16 + c2];
                float4 wa = wl4[((pa.x >> 17) & 15) * 16 + c2];
                float4 wb = wl4[((pb.x >> 17) & 15) * 16 + c2];
                float4 wc = wl4[((pc.x >> 17) & 15) * 16 + c2];
                float4 wd = wl4[((pd.x >> 17) & 15) * 16 + c2];
                float sa = __int_as_float(pa.y);
                float sb = __int_as_float(pb.y);
                float sc = __int_as_float(pc.y);
                float sd = __int_as_float(pd.y);
                v2f wa01 = {wa.x, wa.y}, wa23 = {wa.z, wa.w};
                v2f wb01 = {wb.x, wb.y}, wb23 = {wb.z, wb.w};
                v2f wc01 = {wc.x, wc.y}, wc23 = {wc.z, wc.w};
                v2f wd01 = {wd.x, wd.y}, wd23 = {wd.z, wd.w};
                a01 += bfpair(qa.x) * (wa01 * sa);  a23 += bfpair(qa.y) * (wa23 * sa);
                a01 += bfpair(qb.x) * (wb01 * sb);  a23 += bfpair(qb.y) * (wb23 * sb);
                a01 += bfpair(qc.x) * (wc01 * sc);  a23 += bfpair(qc.y) * (wc23 * sc);
                a01 += bfpair(qd.x) * (wd01 * sd);  a23 += bfpair(qd.y) * (wd23 * sd);
            }
            for (; i + 7 < e; i += 8) {
                int2 pa = sbuf[i + g];
                int2 pb = sbuf[i + 4 + g];
                uint2 qa = cur64[(size_t)(pa.x & 0x1FFFF) * 16 + c2];
                uint2 qb = cur64[(size_t)(pb.x & 0x1FFFF) * 16 + c2];
                float4 wa = wl4[((pa.x >> 17) & 15) * 16 + c2];
                float4 wb = wl4[((pb.x >> 17) & 15) * 16 + c2];
                float sa = __int_as_float(pa.y);
                float sb = __int_as_float(pb.y);
                v2f wa01 = {wa.x, wa.y}, wa23 = {wa.z, wa.w};
                v2f wb01 = {wb.x, wb.y}, wb23 = {wb.z, wb.w};
                a01 += bfpair(qa.x) * (wa01 * sa);  a23 += bfpair(qa.y) * (wa23 * sa);
                a01 += bfpair(qb.x) * (wb01 * sb);  a23 += bfpair(qb.y) * (wb23 * sb);
            }
            for (; i < e; i += 4) {
                int idx = i + g;
                bool vld = idx < e;
                int2 p = sbuf[vld ? idx : i];
                uint2 q = cur64[(size_t)(p.x & 0x1FFFF) * 16 + c2];
                float4 wv = wl4[((p.x >> 17) & 15) * 16 + c2];
                float sv = vld ? __int_as_float(p.y) : 0.f;
                v2f wv01 = {wv.x, wv.y}, wv23 = {wv.z, wv.w};
                a01 += bfpair(q.x) * (wv01 * sv);  a23 += bfpair(q.y) * (wv23 * sv);
            }
        }

        // merge the 4 edge-groups, L2-normalize, res = emb + y
        float x0 = a01.x, x1 = a01.y, x2 = a23.x, x3 = a23.y;
        x0 += __shfl_xor(x0, 16, 64); x0 += __shfl_xor(x0, 32, 64);
        x1 += __shfl_xor(x1, 16, 64); x1 += __shfl_xor(x1, 32, 64);
        x2 += __shfl_xor(x2, 16, 64); x2 += __shfl_xor(x2, 32, 64);
        x3 += __shfl_xor(x3, 16, 64); x3 += __shfl_xor(x3, 32, 64);
        float ss = x0 * x0 + x1 * x1 + x2 * x2 + x3 * x3;
        #pragma unroll
        for (int o = 8; o; o >>= 1) ss += __shfl_xor(ss, o, 64);
        float inv = 1.f / fmaxf(sqrtf(ss), 1e-12f);
        float y0 = x0 * inv, y1 = x1 * inv, y2 = x2 * inv, y3 = x3 * inv;
        if (g == 0) {    // lanes 0-15 hold the complete row; 16B stores
            if (is_user) {
                int grow = b * RPB + row;
                if (grow < N_USERS) {
                    float4 v = src_u[(size_t)grow * 16 + c2];
                    v.x += y0; v.y += y1; v.z += y2; v.w += y3;
                    ((float4*)res_u)[(size_t)grow * 16 + c2] = v;
                }
            } else {
                int grow = eb * RPB + row;
                if (grow < N_ENTITIES) {
                    uint2 pk;
                    pk.x = (unsigned)f2bf(y0) | ((unsigned)f2bf(y1) << 16);
                    pk.y = (unsigned)f2bf(y2) | ((unsigned)f2bf(y3) << 16);
                    ((uint2*)nxt)[(size_t)grow * 16 + c2] = pk;
                    float4 v = src_e[(size_t)grow * 16 + c2];
                    v.x += y0; v.y += y1; v.z += y2; v.w += y3;
                    ((float4*)res_e)[(size_t)grow * 16 + c2] = v;
                }
            }
        }
    }
}

// ---------------------------------------------------------------------------
// Aggregation hop 2 (v9): half-bucket blocks (256 thr = 4 waves), 16-edge
// unroll, 16 lanes/edge, uint2 = 4 packed bf16 channels, packed-f32 math.
// Epilogue: merge 4 groups, L2-normalize, res += y, bf16 next-state.
// ---------------------------------------------------------------------------
__global__ void __launch_bounds__(256)
agg_kernel(const uint2* __restrict__ cur64,    // bf16 quads, 16 uint2/row
           const float* __restrict__ weight,
           const int2* __restrict__ binAll, const int* __restrict__ rowptr,
           unsigned short* __restrict__ nxt,
           const float4* __restrict__ src_e, const float4* __restrict__ src_u,
           float* __restrict__ res_e, float* __restrict__ res_u) {
    __shared__ float4 wl4[N_RELATIONS * 16];   // 4 KB
    __shared__ int    srp[33];

    const int hb = blockIdx.x;       // half-bucket
    const int b = hb >> 1;
    const int half = hb & 1;
    const int t = threadIdx.x;
    const int w = t >> 6;            // wave 0..3
    const int lane = t & 63;
    const int g = lane >> 4;         // edge-group 0..3
    const int c2 = lane & 15;        // uint2 index within row (4 channels)
    const bool is_user = (b < NB_U);
    const int eb = b - NB_U;

    if (!is_user)
        for (int i = t; i < N_RELATIONS * 16; i += 256)
            wl4[i] = ((const float4*)weight)[i];
    if (t < 33) srp[t] = rowptr[b * 65 + half * 32 + t];
    __syncthreads();

    #pragma unroll
    for (int rr = 0; rr < 8; ++rr) {
        const int row_l = (w << 3) + rr;               // 0..31 within half
        const int s = srp[row_l], e = srp[row_l + 1];
        v2f a01 = {0.f, 0.f}, a23 = {0.f, 0.f};
        int i = s;
        if (is_user) {
            for (; i + 15 < e; i += 16) {
                int2 pa = binAll[i + g];
                int2 pb = binAll[i + 4 + g];
                int2 pc = binAll[i + 8 + g];
                int2 pd = binAll[i + 12 + g];
                uint2 qa = cur64[(size_t)(pa.x & 0x1FFFF) * 16 + c2];
                uint2 qb = cur64[(size_t)(pb.x & 0x1FFFF) * 16 + c2];
                uint2 qc = cur64[(size_t)(pc.x & 0x1FFFF) * 16 + c2];
                uint2 qd = cur64[(size_t)(pd.x & 0x1FFFF) * 16 + c2];
                float sa = __int_as_float(pa.y);
                float sb = __int_as_float(pb.y);
                float sc = __int_as_float(pc.y);
                float sd = __int_as_float(pd.y);
                a01 += bfpair(qa.x) * sa;  a23 += bfpair(qa.y) * sa;
                a01 += bfpair(qb.x) * sb;  a23 += bfpair(qb.y) * sb;
                a01 += bfpair(qc.x) * sc;  a23 += bfpair(qc.y) * sc;
                a01 += bfpair(qd.x) * sd;  a23 += bfpair(qd.y) * sd;
            }
            for (; i + 7 < e; i += 8) {
                int2 pa = binAll[i + g];
                int2 pb = binAll[i + 4 + g];
                uint2 qa = cur64[(size_t)(pa.x & 0x1FFFF) * 16 + c2];
                uint2 qb = cur64[(size_t)(pb.x & 0x1FFFF) * 16 + c2];
                float sa = __int_as_float(pa.y);
                float sb = __int_as_float(pb.y);
                a01 += bfpair(qa.x) * sa;  a23 += bfpair(qa.y) * sa;
                a01 += bfpair(qb.x) * sb;  a23 += bfpair(qb.y) * sb;
            }
            for (; i < e; i += 4) {          // masked 4-edge tail
                int idx = i + g;
                bool vld = idx < e;
                int2 p = binAll[vld ? idx : i];
                uint2 q = cur64[(size_t)(p.x & 0x1FFFF) * 16 + c2];
                float sv = vld ? __int_as_float(p.y) : 0.f;
                a01 += bfpair(q.x) * sv;  a23 += bfpair(q.y) * sv;
            }
        } else {
            for (; i + 15 < e; i += 16) {
                int2 pa = binAll[i + g];
                int2 pb = binAll[i + 4 + g];
                int2 pc = binAll[i + 8 + g];
                int2 pd = binAll[i + 12 + g];
                uint2 qa = cur64[(size_t)(pa.x & 0x1FFFF) * 16 + c2];
                uint2 qb = cur64[(size_t)(pb.x & 0x1FFFF) * 16 + c2];
                uint2 qc = cur64[(size_t)(pc.x & 0x1FFFF) * 16 + c2];
                uint2 qd = cur64[(size_t)(pd.x & 0x1FFFF) * 16 + c2];
                float4 wa = wl4[((pa.x >> 17) & 15) * 16 + c2];
                float4 wb = wl4[((pb.x >> 17) & 15) * 16 + c2];
                float4 wc = wl4[((pc.x >> 17) & 15) * 16 + c2];
                float4 wd = wl4[((pd.x >> 17) & 15) * 16 + c2];
                float sa = __int_as_float(pa.y);
                float sb = __int_as_float(pb.y);
                float sc = __int_as_float(pc.y);
                float sd = __int_as_float(pd.y);
                v2f wa01 = {wa.x, wa.y}, wa23 = {wa.z, wa.w};
                v2f wb01 = {wb.x, wb.y}, wb23 = {wb.z, wb.w};
                v2f wc01 = {wc.x, wc.y}, wc23 = {wc.z, wc.w};
                v2f wd01 = {wd.x, wd.y}, wd23 = {wd.z, wd.w};
                a01 += bfpair(qa.x) * (wa01 * sa);  a23 += bfpair(qa.y) * (wa23 * sa);
                a01 += bfpair(qb.x) * (wb01 * sb);  a23 += bfpair(qb.y) * (wb23 * sb);
                a01 += bfpair(qc.x) * (wc01 * sc);  a23 += bfpair(qc.y) * (wc23 * sc);
                a01 += bfpair(qd.x) * (wd01 * sd);  a23 += bfpair(qd.y) * (wd23 * sd);
            }
            for (; i + 7 < e; i += 8) {
                int2 pa = binAll[i + g];
                int2 pb = binAll[i + 4 + g];
                uint2 qa = cur64[(size_t)(pa.x & 0x1FFFF) * 16 + c2];
                uint2 qb = cur64[(size_t)(pb.x & 0x1FFFF) * 16 + c2];
                float4 wa = wl4[((pa.x >> 17) & 15) * 16 + c2];
                float4 wb = wl4[((pb.x >> 17) & 15) * 16 + c2];
                float sa = __int_as_float(pa.y);
                float sb = __int_as_float(pb.y);
                v2f wa01 = {wa.x, wa.y}, wa23 = {wa.z, wa.w};
                v2f wb01 = {wb.x, wb.y}, wb23 = {wb.z, wb.w};
                a01 += bfpair(qa.x) * (wa01 * sa);  a23 += bfpair(qa.y) * (wa23 * sa);
                a01 += bfpair(qb.x) * (wb01 * sb);  a23 += bfpair(qb.y) * (wb23 * sb);
            }
            for (; i < e; i += 4) {
                int idx = i + g;
                bool vld = idx < e;
                int2 p = binAll[vld ? idx : i];
                uint2 q = cur64[(size_t)(p.x & 0x1FFFF) * 16 + c2];
                float4 wv = wl4[((p.x >> 17) & 15) * 16 + c2];
                float sv = vld ? __int_as_float(p.y) : 0.f;
                v2f wv01 = {wv.x, wv.y}, wv23 = {wv.z, wv.w};
                a01 += bfpair(q.x) * (wv01 * sv);  a23 += bfpair(q.y) * (wv23 * sv);
            }
        }

        // merge the 4 edge-groups
        float x0 = a01.x, x1 = a01.y, x2 = a23.x, x3 = a23.y;
        x0 += __shfl_xor(x0, 16, 64); x0 += __shfl_xor(x0, 32, 64);
        x1 += __shfl_xor(x1, 16, 64); x1 += __shfl_xor(x1, 32, 64);
        x2 += __shfl_xor(x2, 16, 64); x2 += __shfl_xor(x2, 32, 64);
        x3 += __shfl_xor(x3, 16, 64); x3 += __shfl_xor(x3, 32, 64);
        float ss = x0 * x0 + x1 * x1 + x2 * x2 + x3 * x3;
        #pragma unroll
        for (int o = 8; o; o >>= 1) ss += __shfl_xor(ss, o, 64);
        float inv = 1.f / fmaxf(sqrtf(ss), 1e-12f);
        float y0 = x0 * inv, y1 = x1 * inv, y2 = x2 * inv, y3 = x3 * inv;
        if (g == 0) {    // lanes 0-15 hold the complete row; 16B stores
            const int lrow = half * 32 + row_l;
            if (is_user) {
                int grow = b * RPB + lrow;
                if (grow < N_USERS) {
                    float4 v = src_u[(size_t)grow * 16 + c2];
                    v.x += y0; v.y += y1; v.z += y2; v.w += y3;
                    ((float4*)res_u)[(size_t)grow * 16 + c2] = v;
                }
            } else {
                int grow = eb * RPB + lrow;
                if (grow < N_ENTITIES) {
                    uint2 pk;
                    pk.x = (unsigned)f2bf(y0) | ((unsigned)f2bf(y1) << 16);
                    pk.y = (unsigned)f2bf(y2) | ((unsigned)f2bf(y3) << 16);
                    ((uint2*)nxt)[(size_t)grow * 16 + c2] = pk;
                    float4 v = src_e[(size_t)grow * 16 + c2];
                    v.x += y0; v.y += y1; v.z += y2; v.w += y3;
                    ((float4*)res_e)[(size_t)grow * 16 + c2] = v;
                }
            }
        }
    }
}

extern "C" void kernel_launch(void* const* d_in, const int* in_sizes, int n_in,
                              void* d_out, int out_size, void* d_ws, size_t ws_size,
                              hipStream_t stream) {
    const float* user_emb   = (const float*)d_in[0];
    const float* entity_emb = (const float*)d_in[1];
    const float* weight     = (const float*)d_in[2];
    const float* mask       = (const float*)d_in[3];
    const float* ivals      = (const float*)d_in[4];
    const int*   edge_head  = (const int*)d_in[5];
    const int*   edge_tail  = (const int*)d_in[6];
    const int*   edge_type  = (const int*)d_in[7];
    const int*   irows      = (const int*)d_in[8];
    const int*   icols      = (const int*)d_in[9];

    float* out_entity = (float*)d_out;
    float* out_user   = (float*)d_out + (size_t)N_ENTITIES * CH;

    // ---- d_out doubles as coarse-bin scratch until sortagg rewrites it ----
    int2* cbE   = (int2*)d_out;                          // 49*67072*8 = 26.29 MB
    int2* cbU_d = cbE + (size_t)NCE * CAPC_E;            // 14*104448*8 = 11.70 MB

    // ---- workspace layout (~81.0 MB) ----
    unsigned short* curA = (unsigned short*)d_ws;                    // 12.8 MB
    unsigned short* curB = curA + (size_t)N_ENTITIES * CH;           // 12.8 MB
    int2* binAll = (int2*)(curB + (size_t)N_ENTITIES * CH);          // 45.6 MB
    int2* cbU_w  = binAll + (size_t)(N_EDGES + NNZ);                 // 9.19 MB
    int*  fineCnt  = (int*)(cbU_w + (size_t)(NCU - NCU_DOUT) * CAPC_U);
    int*  cCurE    = fineCnt + NBUCKETS;                             // 49
    int*  cCurU    = cCurE + NCE;                                    // 25
    int*  fineBase = cCurU + NCU;                                    // 2345
    int*  fineCur  = fineBase + NBUCKETS;                            // 2345
    int*  rowptr   = fineCur + NBUCKETS;                             // 2345*65

    hipMemsetAsync(fineCnt, 0, (size_t)(NBUCKETS + NCE + NCU) * sizeof(int), stream);

    // ---- pass A: coarse partition + exact fine counts + bf16 pack ----
    passA_kernel<<<PA_KG + PA_U + PACK_BLOCKS, 1024, 0, stream>>>(
        edge_head, edge_tail, edge_type, mask, irows, icols, ivals,
        (const float4*)entity_emb, (ushort4*)curA,
        fineCnt, cCurE, cCurU, cbE, cbU_d, cbU_w);

    // ---- exclusive scan -> exact CSR bases + pass-B cursors ----
    scan_kernel<<<1, 512, 0, stream>>>(fineCnt, fineBase, fineCur);

    // ---- pass B: fine partition into exact CSR (per-block reservations) ----
    passB_kernel<<<NCE * SE + NCU * SU, 1024, 0, stream>>>(
        cCurE, cCurU, cbE, cbU_d, cbU_w, fineCur, binAll);

    // ---- fused sort + hop 1 (res = emb + y) ----
    sortagg_kernel<<<NBUCKETS, 512, 0, stream>>>(
        binAll, fineCnt, fineBase, rowptr,
        (const uint2*)curA, weight, curB,
        (const float4*)entity_emb, (const float4*)user_emb,
        out_entity, out_user);

    // ---- hop 2 (res += y) ----
    agg_kernel<<<2 * NBUCKETS, 256, 0, stream>>>(
        (const uint2*)curB, weight, binAll, rowptr, curA,
        (const float4*)out_entity, (const float4*)out_user,
        out_entity, out_user);
}